// Round 1
// baseline (2901.121 us; speedup 1.0000x reference)
//
#include <hip/hip_runtime.h>
#include <cstdint>
#include <cstddef>

// Problem constants
#define B_  4096
#define H_  300
#define T_  43
#define NC_ 80
#define HP  320      // padded K per region (x part / h part), multiple of 32
#define KT  640      // total GEMM K (x 0..319, h 320..639)
#define NP  1280     // padded N per direction (1200 real -> 10 tiles of 128)
#define NR  1200

typedef _Float16 f16;
typedef _Float16 half8 __attribute__((ext_vector_type(8)));
typedef float    f32x4 __attribute__((ext_vector_type(4)));

__device__ __forceinline__ void gl_lds16(const void* g, void* l) {
  __builtin_amdgcn_global_load_lds(
      (const __attribute__((address_space(1))) void*)g,
      (__attribute__((address_space(3))) void*)l, 16, 0, 0);
}
__device__ __forceinline__ float sigmoid_(float x) {
  return 1.f / (1.f + __expf(-x));
}
__device__ __forceinline__ float tanh_fast(float x) {
  x = fminf(fmaxf(x, -15.f), 15.f);
  float e = __expf(2.f * x);
  return (e - 1.f) / (e + 1.f);
}

// ---------------------------------------------------------------------------
// Weight packing: Wc[d][n][k], n = 4*jh + gate (gate order i,f,g,o),
// k<320: w_ih (k<300 real), k>=320: w_hh. Zero padding everywhere else.
// biasC[d][n] = b_ih + b_hh, gate-interleaved.
// ---------------------------------------------------------------------------
__global__ void prep_weights(const float* __restrict__ w_ih,
                             const float* __restrict__ w_hh,
                             const float* __restrict__ b_ih,
                             const float* __restrict__ b_hh,
                             f16* __restrict__ Wc, float* __restrict__ biasC) {
  int idx = blockIdx.x * 256 + threadIdx.x;
  const int total = 2 * NP * KT;
  if (idx < total) {
    int d = idx / (NP * KT);
    int rem = idx % (NP * KT);
    int n = rem / KT, k = rem % KT;
    int jh = n >> 2, g = n & 3;
    float v = 0.f;
    if (jh < H_) {
      if (k < HP) {
        if (k < H_) v = w_ih[((size_t)d * 4 * H_ + g * H_ + jh) * H_ + k];
      } else {
        int kk = k - HP;
        if (kk < H_) v = w_hh[((size_t)d * 4 * H_ + g * H_ + jh) * H_ + kk];
      }
    }
    Wc[idx] = (f16)v;
  }
  if (idx < 2 * NP) {
    int d = idx / NP, n = idx % NP;
    int jh = n >> 2, g = n & 3;
    float v = 0.f;
    if (jh < H_)
      v = b_ih[d * 4 * H_ + g * H_ + jh] + b_hh[d * 4 * H_ + g * H_ + jh];
    biasC[idx] = v;
  }
}

// ---------------------------------------------------------------------------
// x [B,H,T] fp32 -> xT[t][b][k] f16, k padded to 320 with zeros.
// LDS transpose so both global read and write are contiguous.
// ---------------------------------------------------------------------------
__global__ void prep_xT(const float* __restrict__ x, f16* __restrict__ xT) {
  __shared__ float tile[64][44];
  int b = blockIdx.x, ch = blockIdx.y;
  int h0 = ch * 64;
  for (int idx = threadIdx.x; idx < 64 * T_; idx += 256) {
    int hh = idx / T_, t = idx % T_;
    float v = 0.f;
    if (h0 + hh < H_) v = x[((size_t)b * H_ + h0 + hh) * T_ + t];
    tile[hh][t] = v;
  }
  __syncthreads();
  for (int idx = threadIdx.x; idx < 64 * T_; idx += 256) {
    int t = idx / 64, hh = idx % 64;
    xT[((size_t)t * B_ + b) * HP + h0 + hh] = (f16)tile[hh][t];
  }
}

// ---------------------------------------------------------------------------
// One LSTM time step, both directions:
//   z[d,b,n] = [x_t | h_prev_d] @ Wc_d^T + bias  (M=4096, N=1280, K=640)
// fused gate epilogue -> c (fp32, in-place), h_next (f16, ping-pong),
// hs_t (f16, for attention).
// m97 structure: 128x128 tile, 4 waves (2x2 of 64x64), mfma 16x16x32 f16,
// global_load_lds width 16.
// ---------------------------------------------------------------------------
__global__ void lstm_step(const f16* __restrict__ xT_t,    // [B_][HP]
                          const f16* __restrict__ h_prev,  // [2][B_][HP]
                          f16* __restrict__ h_next,        // [2][B_][HP]
                          float* __restrict__ c,           // [2][B_][H_]
                          const f16* __restrict__ Wc,      // [2][NP][KT]
                          const float* __restrict__ biasC, // [2][NP]
                          f16* __restrict__ hs_t)          // [2][B_][H_]
{
  __shared__ f16 As[128 * 32];
  __shared__ f16 Bs[128 * 32];
  const int tid = threadIdx.x;
  const int wave = tid >> 6, lane = tid & 63;
  const int mt = blockIdx.x, nt = blockIdx.y, d = blockIdx.z;

  const f16* Wd = Wc + (size_t)d * NP * KT + (size_t)nt * 128 * KT;
  const f16* hp = h_prev + (size_t)d * B_ * HP;

  const int lrow4 = lane >> 2;        // 0..15: row within 16-row chunk
  const int col8  = (lane & 3) << 3;  // 0,8,16,24: k offset

  f32x4 acc[4][4];
#pragma unroll
  for (int i = 0; i < 4; i++)
#pragma unroll
    for (int j = 0; j < 4; j++) acc[i][j] = (f32x4){0.f, 0.f, 0.f, 0.f};

  const int wm = wave & 1, wn = wave >> 1;
  const int lr = lane & 15;
  const int kq = (lane >> 4) << 3;

  for (int kt = 0; kt < KT / 32; ++kt) {
    const f16* srcA = (kt < HP / 32) ? (xT_t + kt * 32) : (hp + (kt - HP / 32) * 32);
    const int kcolB = kt * 32;
    __syncthreads();  // previous iter's LDS reads complete
#pragma unroll
    for (int i = 0; i < 2; i++) {
      int r0 = wave * 32 + i * 16;
      gl_lds16(srcA + (size_t)(mt * 128 + r0 + lrow4) * HP + col8,
               &As[r0 * 32]);
      gl_lds16(Wd + (size_t)(r0 + lrow4) * KT + kcolB + col8,
               &Bs[r0 * 32]);
    }
    __syncthreads();  // drains vmcnt (global_load_lds) per CDNA4 barrier semantics

    half8 af[4], bf[4];
#pragma unroll
    for (int i = 0; i < 4; i++) {
      af[i] = *(const half8*)&As[(wm * 64 + i * 16 + lr) * 32 + kq];
      bf[i] = *(const half8*)&Bs[(wn * 64 + i * 16 + lr) * 32 + kq];
    }
#pragma unroll
    for (int i = 0; i < 4; i++)
#pragma unroll
      for (int j = 0; j < 4; j++)
        acc[i][j] = __builtin_amdgcn_mfma_f32_16x16x32_f16(af[i], bf[j],
                                                           acc[i][j], 0, 0, 0);
  }

  // Epilogue: bias + gates. n = 4*jh + gate, gates (i,f,g,o) in adjacent lanes.
  float bj[4];
#pragma unroll
  for (int j = 0; j < 4; j++)
    bj[j] = biasC[d * NP + nt * 128 + wn * 64 + j * 16 + lr];

#pragma unroll
  for (int i = 0; i < 4; i++) {
    const int brow = mt * 128 + wm * 64 + i * 16 + ((lane >> 4) << 2);
#pragma unroll
    for (int j = 0; j < 4; j++) {
      const int col = nt * 128 + wn * 64 + j * 16 + lr;
#pragma unroll
      for (int r = 0; r < 4; r++) {
        float z = acc[i][j][r] + bj[j];
        float zf = __shfl_down(z, 1);
        float zg = __shfl_down(z, 2);
        float zo = __shfl_down(z, 3);
        if ((lane & 3) == 0) {
          int jh = col >> 2;
          if (jh < H_) {
            int b = brow + r;
            size_t cidx = ((size_t)d * B_ + b) * H_ + jh;
            float co = c[cidx];
            float ig = sigmoid_(z);
            float fg = sigmoid_(zf);
            float gg = tanh_fast(zg);
            float og = sigmoid_(zo);
            float cn = fg * co + ig * gg;
            float hn = og * tanh_fast(cn);
            c[cidx] = cn;
            h_next[((size_t)d * B_ + b) * HP + jh] = (f16)hn;
            hs_t[((size_t)d * B_ + b) * H_ + jh] = (f16)hn;
          }
        }
      }
    }
  }
}

// ---------------------------------------------------------------------------
// Attention + FC + softmax. One block per batch row; [43][300] slice in LDS.
// ---------------------------------------------------------------------------
__global__ __launch_bounds__(256) void attn(const f16* __restrict__ hs,  // [T_][2][B_][H_]
                                            const float* __restrict__ conv_w,
                                            const float* __restrict__ fc_w,
                                            const float* __restrict__ fc_b,
                                            float* __restrict__ out) {
  __shared__ float hsum[T_][304];
  __shared__ float red[80];
  __shared__ float hstar[304];
  __shared__ float lg[80];
  __shared__ float mxs, sms;
  const int b = blockIdx.x, tid = threadIdx.x;
  const int wave = tid >> 6, lane = tid & 63;

  for (int idx = tid; idx < T_ * H_; idx += 256) {
    int t = idx / H_, jh = idx % H_;
    float v = (float)hs[(((size_t)t * 2 + 0) * B_ + b) * H_ + jh] +
              (float)hs[(((size_t)t * 2 + 1) * B_ + b) * H_ + jh];
    hsum[t][jh] = v;
  }
  __syncthreads();

  // alpha logits: per wave, strided over t
  for (int t = wave; t < T_; t += 4) {
    float p = 0.f;
    for (int jh = lane; jh < H_; jh += 64)
      p += tanh_fast(hsum[t][jh]) * conv_w[jh];
#pragma unroll
    for (int o = 32; o; o >>= 1) p += __shfl_down(p, o);
    if (lane == 0) red[t] = p;
  }
  __syncthreads();

  // softmax over T_ (one wave)
  if (tid < 64) {
    float a = (tid < T_) ? red[tid] : -1e30f;
    float mx = a;
#pragma unroll
    for (int o = 32; o; o >>= 1) mx = fmaxf(mx, __shfl_xor(mx, o));
    float e = (tid < T_) ? __expf(a - mx) : 0.f;
    float s = e;
#pragma unroll
    for (int o = 32; o; o >>= 1) s += __shfl_xor(s, o);
    if (tid < T_) red[tid] = e / s;
  }
  __syncthreads();

  // r = hsum @ alpha ; hStar = tanh(r)
  for (int jh = tid; jh < H_; jh += 256) {
    float r = 0.f;
#pragma unroll
    for (int t = 0; t < T_; t++) r += hsum[t][jh] * red[t];
    hstar[jh] = tanh_fast(r);
  }
  __syncthreads();

  // logits
  if (tid < NC_) {
    float o = fc_b[tid];
    const float* fw = fc_w + (size_t)tid * H_;
    for (int k = 0; k < H_; k++) o += hstar[k] * fw[k];
    lg[tid] = o;
  }
  __syncthreads();
  if (tid == 0) {
    float mx = -1e30f;
    for (int i2 = 0; i2 < NC_; i2++) mx = fmaxf(mx, lg[i2]);
    float s = 0.f;
    for (int i2 = 0; i2 < NC_; i2++) s += __expf(lg[i2] - mx);
    mxs = mx; sms = s;
  }
  __syncthreads();
  if (tid < NC_) out[(size_t)b * NC_ + tid] = __expf(lg[tid] - mxs) / sms;
}

// ---------------------------------------------------------------------------
extern "C" void kernel_launch(void* const* d_in, const int* in_sizes, int n_in,
                              void* d_out, int out_size, void* d_ws, size_t ws_size,
                              hipStream_t stream) {
  const float* x      = (const float*)d_in[0];
  const float* w_ih   = (const float*)d_in[1];
  const float* w_hh   = (const float*)d_in[2];
  const float* b_ih   = (const float*)d_in[3];
  const float* b_hh   = (const float*)d_in[4];
  const float* conv_w = (const float*)d_in[5];
  const float* fc_w   = (const float*)d_in[6];
  const float* fc_b   = (const float*)d_in[7];
  float* out = (float*)d_out;

  // Workspace layout (~332 MB total)
  char* p = (char*)d_ws;
  f16* Wc = (f16*)p;        p += (size_t)2 * NP * KT * sizeof(f16);       // 3.125 MB
  float* biasC = (float*)p; p += (size_t)2 * NP * sizeof(float);          // 10 KB
  f16* xT = (f16*)p;        p += (size_t)T_ * B_ * HP * sizeof(f16);      // 107.5 MB
  f16* h  = (f16*)p;        p += (size_t)2 * 2 * B_ * HP * sizeof(f16);   // 10 MB (ping-pong x dirs)
  float* c = (float*)p;     p += (size_t)2 * B_ * H_ * sizeof(float);     // 9.4 MB
  f16* hs = (f16*)p;        p += (size_t)T_ * 2 * B_ * H_ * sizeof(f16);  // 201.6 MB

  hipMemsetAsync(h, 0, (size_t)2 * 2 * B_ * HP * sizeof(f16), stream);
  hipMemsetAsync(c, 0, (size_t)2 * B_ * H_ * sizeof(float), stream);

  prep_weights<<<(2 * NP * KT + 255) / 256, 256, 0, stream>>>(
      w_ih, w_hh, b_ih, b_hh, Wc, biasC);
  prep_xT<<<dim3(B_, 5), 256, 0, stream>>>(x, xT);

  for (int t = 0; t < T_; ++t) {
    const f16* hprev = h + (size_t)(t & 1) * 2 * B_ * HP;
    f16* hnext      = h + (size_t)((t + 1) & 1) * 2 * B_ * HP;
    lstm_step<<<dim3(32, 10, 2), 256, 0, stream>>>(
        xT + (size_t)t * B_ * HP, hprev, hnext, c, Wc, biasC,
        hs + (size_t)t * 2 * B_ * H_);
  }

  attn<<<B_, 256, 0, stream>>>(hs, conv_w, fc_w, fc_b, out);
}

// Round 2
// 2756.924 us; speedup vs baseline: 1.0523x; 1.0523x over previous
//
#include <hip/hip_runtime.h>
#include <cstdint>
#include <cstddef>

// Problem constants
#define B_  4096
#define H_  300
#define T_  43
#define NC_ 80
#define HP  320      // padded K (input/hidden dim 300 -> 320)
#define ND  1280     // padded 4H per direction (1200 -> 1280)
#define NDD 2560     // both directions
#define SB  12912    // hs per-(d,b) stride in f16 (43*300=12900, pad to /16 bytes)
#define XZC 4        // xz precompute chunk (timesteps)

typedef _Float16 f16;
typedef _Float16 half8 __attribute__((ext_vector_type(8)));
typedef _Float16 half4 __attribute__((ext_vector_type(4)));
typedef float    f32x4 __attribute__((ext_vector_type(4)));

__device__ __forceinline__ void gl_lds16(const void* g, void* l) {
  __builtin_amdgcn_global_load_lds(
      (const __attribute__((address_space(1))) void*)g,
      (__attribute__((address_space(3))) void*)l, 16, 0, 0);
}
__device__ __forceinline__ float sigmoid_(float x) {
  return 1.f / (1.f + __expf(-x));
}
__device__ __forceinline__ float tanh_fast(float x) {
  x = fminf(fmaxf(x, -15.f), 15.f);
  float e = __expf(2.f * x);
  return (e - 1.f) / (e + 1.f);
}

// ---------------------------------------------------------------------------
// Weight packing. Row index = d*1280 + 4*jh + g (gate-interleaved, order
// i,f,g,o). Wih[2560][320] (k<300 real), Whh[2560][320], bias[2560].
// ---------------------------------------------------------------------------
__global__ void prep_weights(const float* __restrict__ w_ih,
                             const float* __restrict__ w_hh,
                             const float* __restrict__ b_ih,
                             const float* __restrict__ b_hh,
                             f16* __restrict__ Wih, f16* __restrict__ Whh,
                             float* __restrict__ bias) {
  int idx = blockIdx.x * 256 + threadIdx.x;
  const int total = NDD * HP;
  if (idx < 2 * total) {
    int which = idx / total;  // 0 = Wih, 1 = Whh
    int rem = idx % total;
    int row = rem / HP, k = rem % HP;
    int d = row / ND, n = row % ND;
    int jh = n >> 2, g = n & 3;
    float v = 0.f;
    if (jh < H_ && k < H_) {
      const float* W = which ? w_hh : w_ih;
      v = W[((size_t)d * 4 * H_ + g * H_ + jh) * H_ + k];
    }
    (which ? Whh : Wih)[(size_t)row * HP + k] = (f16)v;
  }
  if (idx < NDD) {
    int d = idx / ND, n = idx % ND;
    int jh = n >> 2, g = n & 3;
    float v = 0.f;
    if (jh < H_)
      v = b_ih[d * 4 * H_ + g * H_ + jh] + b_hh[d * 4 * H_ + g * H_ + jh];
    bias[idx] = v;
  }
}

// ---------------------------------------------------------------------------
// x [B,H,T] fp32 -> xT[t*B+b][k] f16, k padded to 320 with zeros.
// ---------------------------------------------------------------------------
__global__ void prep_xT(const float* __restrict__ x, f16* __restrict__ xT) {
  __shared__ float tile[64][44];
  int b = blockIdx.x, ch = blockIdx.y;
  int h0 = ch * 64;
  for (int idx = threadIdx.x; idx < 64 * T_; idx += 256) {
    int hh = idx / T_, t = idx % T_;
    float v = 0.f;
    if (h0 + hh < H_) v = x[((size_t)b * H_ + h0 + hh) * T_ + t];
    tile[hh][t] = v;
  }
  __syncthreads();
  for (int idx = threadIdx.x; idx < 64 * T_; idx += 256) {
    int t = idx / 64, hh = idx % 64;
    xT[((size_t)t * B_ + b) * HP + h0 + hh] = (f16)tile[hh][t];
  }
}

// ---------------------------------------------------------------------------
// Precompute xz[m][n] = xT_chunk[m] @ Wih^T  (m = t_local*B+b, n = d*1280+..)
// M = cn*4096, N = 2560, K = 320.  A = x rows, B = weight rows, C[m][n] f16.
// ---------------------------------------------------------------------------
__global__ void xz_gemm(const f16* __restrict__ A,    // [M][320]
                        const f16* __restrict__ Wih,  // [2560][320]
                        f16* __restrict__ xz) {       // [M][2560]
  __shared__ f16 As[128 * 32];
  __shared__ f16 Bs[128 * 32];
  const int tid = threadIdx.x;
  const int wave = tid >> 6, lane = tid & 63;
  const int mt = blockIdx.x, nt = blockIdx.y;
  const int lrow4 = lane >> 2, col8 = (lane & 3) << 3;
  const int wm = wave & 1, wn = wave >> 1;
  const int lr = lane & 15, kq = (lane >> 4) << 3;

  const f16* Ab = A + (size_t)mt * 128 * HP;
  const f16* Bb = Wih + (size_t)nt * 128 * HP;

  f32x4 acc[4][4];
#pragma unroll
  for (int i = 0; i < 4; i++)
#pragma unroll
    for (int j = 0; j < 4; j++) acc[i][j] = (f32x4){0.f, 0.f, 0.f, 0.f};

  for (int kt = 0; kt < HP / 32; ++kt) {
    __syncthreads();
#pragma unroll
    for (int i = 0; i < 2; i++) {
      int r0 = wave * 32 + i * 16;
      gl_lds16(Ab + (size_t)(r0 + lrow4) * HP + kt * 32 + col8, &As[r0 * 32]);
      gl_lds16(Bb + (size_t)(r0 + lrow4) * HP + kt * 32 + col8, &Bs[r0 * 32]);
    }
    __syncthreads();
    half8 af[4], bf[4];
#pragma unroll
    for (int i = 0; i < 4; i++) {
      af[i] = *(const half8*)&As[(wm * 64 + i * 16 + lr) * 32 + kq];
      bf[i] = *(const half8*)&Bs[(wn * 64 + i * 16 + lr) * 32 + kq];
    }
#pragma unroll
    for (int i = 0; i < 4; i++)
#pragma unroll
      for (int j = 0; j < 4; j++)
        acc[i][j] = __builtin_amdgcn_mfma_f32_16x16x32_f16(af[i], bf[j],
                                                           acc[i][j], 0, 0, 0);
  }
#pragma unroll
  for (int i = 0; i < 4; i++) {
    const int m0 = mt * 128 + wm * 64 + i * 16 + ((lane >> 4) << 2);
#pragma unroll
    for (int j = 0; j < 4; j++) {
      const int n = nt * 128 + wn * 64 + j * 16 + lr;
#pragma unroll
      for (int r = 0; r < 4; r++)
        xz[(size_t)(m0 + r) * NDD + n] = (f16)acc[i][j][r];
    }
  }
}

// ---------------------------------------------------------------------------
// One LSTM step, z^T orientation: A = Whh rows (n-dim), B = h_prev rows
// (batch). Each lane's 4 acc regs = the 4 gates (i,f,g,o) of one jh.
// All 64 lanes active in epilogue, no shuffles.
// grid (10 n-tiles, 32 b-tiles, 2 dirs), 256 thr.
// ---------------------------------------------------------------------------
__global__ void lstm_step(const f16* __restrict__ h_prev,  // [2][B][320]
                          f16* __restrict__ h_next,        // [2][B][320]
                          float* __restrict__ c,           // [2][300][B]
                          const f16* __restrict__ Whh,     // [2560][320]
                          const float* __restrict__ bias,  // [2560]
                          const f16* __restrict__ xz_t,    // [B][2560]
                          f16* __restrict__ hs_t)          // hs + t*300
{
  __shared__ f16 As[128 * 32];
  __shared__ f16 Bs[128 * 32];
  const int tid = threadIdx.x;
  const int wave = tid >> 6, lane = tid & 63;
  const int wt = blockIdx.x, bt = blockIdx.y, d = blockIdx.z;
  const int lrow4 = lane >> 2, col8 = (lane & 3) << 3;
  const int wm = wave & 1, wn = wave >> 1;
  const int lr = lane & 15, lq = lane >> 4;
  const int kq = lq << 3;

  const f16* Wb = Whh + ((size_t)d * ND + wt * 128) * HP;
  const f16* hb = h_prev + ((size_t)d * B_ + bt * 128) * HP;

  f32x4 acc[4][4];
#pragma unroll
  for (int i = 0; i < 4; i++)
#pragma unroll
    for (int j = 0; j < 4; j++) acc[i][j] = (f32x4){0.f, 0.f, 0.f, 0.f};

  for (int kt = 0; kt < HP / 32; ++kt) {
    __syncthreads();
#pragma unroll
    for (int i = 0; i < 2; i++) {
      int r0 = wave * 32 + i * 16;
      gl_lds16(Wb + (size_t)(r0 + lrow4) * HP + kt * 32 + col8, &As[r0 * 32]);
      gl_lds16(hb + (size_t)(r0 + lrow4) * HP + kt * 32 + col8, &Bs[r0 * 32]);
    }
    __syncthreads();
    half8 af[4], bf[4];
#pragma unroll
    for (int i = 0; i < 4; i++) {
      af[i] = *(const half8*)&As[(wm * 64 + i * 16 + lr) * 32 + kq];
      bf[i] = *(const half8*)&Bs[(wn * 64 + i * 16 + lr) * 32 + kq];
    }
#pragma unroll
    for (int i = 0; i < 4; i++)
#pragma unroll
      for (int j = 0; j < 4; j++)
        acc[i][j] = __builtin_amdgcn_mfma_f32_16x16x32_f16(af[i], bf[j],
                                                           acc[i][j], 0, 0, 0);
  }

  // Epilogue: lane handles jh = wt*32 + wm*16 + i*4 + lq, batch b per j.
#pragma unroll
  for (int i = 0; i < 4; i++) {
    const int jh = wt * 32 + wm * 16 + i * 4 + lq;
    if (jh >= H_) continue;
    const float4 b4 = *(const float4*)&bias[d * ND + 4 * jh];
#pragma unroll
    for (int j = 0; j < 4; j++) {
      const int b = bt * 128 + wn * 64 + j * 16 + lr;
      const half4 x4 = *(const half4*)&xz_t[(size_t)b * NDD + d * ND + 4 * jh];
      float zi = acc[i][j][0] + b4.x + (float)x4[0];
      float zf = acc[i][j][1] + b4.y + (float)x4[1];
      float zg = acc[i][j][2] + b4.z + (float)x4[2];
      float zo = acc[i][j][3] + b4.w + (float)x4[3];
      const size_t cidx = ((size_t)d * H_ + jh) * B_ + b;
      float co = c[cidx];
      float cn = sigmoid_(zf) * co + sigmoid_(zi) * tanh_fast(zg);
      float hn = sigmoid_(zo) * tanh_fast(cn);
      c[cidx] = cn;
      h_next[((size_t)d * B_ + b) * HP + jh] = (f16)hn;
      hs_t[((size_t)d * B_ + b) * SB + jh] = (f16)hn;
    }
  }
}

// ---------------------------------------------------------------------------
// Attention + FC + softmax. hs[d][b] is a contiguous [43*300] f16 slab
// (stride SB) -> vectorized half8 staging into LDS.
// ---------------------------------------------------------------------------
__global__ __launch_bounds__(256) void attn(const f16* __restrict__ hs,
                                            const float* __restrict__ conv_w,
                                            const float* __restrict__ fc_w,
                                            const float* __restrict__ fc_b,
                                            float* __restrict__ out) {
  __shared__ float hsum[T_ * H_];  // 12900 floats, 51.6 KB
  __shared__ float cw[H_];
  __shared__ float alpha[64];
  __shared__ float hstar[H_];
  __shared__ float lg[NC_];
  __shared__ float mxs, sms;
  const int b = blockIdx.x, tid = threadIdx.x;
  const int wave = tid >> 6, lane = tid & 63;

  for (int k = tid; k < H_; k += 256) cw[k] = conv_w[k];

  const f16* s0 = hs + (size_t)b * SB;
  const f16* s1 = hs + (size_t)(B_ + b) * SB;
  for (int idx = tid * 8; idx + 8 <= T_ * H_; idx += 2048) {
    half8 a = *(const half8*)(s0 + idx);
    half8 c8 = *(const half8*)(s1 + idx);
#pragma unroll
    for (int r = 0; r < 8; r++) hsum[idx + r] = (float)a[r] + (float)c8[r];
  }
  if (tid < 4) {
    int idx = (T_ * H_ / 8) * 8 + tid;  // 12896..12899
    hsum[idx] = (float)s0[idx] + (float)s1[idx];
  }
  __syncthreads();

  // alpha logits over t
  for (int t = wave; t < T_; t += 4) {
    float p = 0.f;
    for (int k = lane; k < H_; k += 64)
      p += tanh_fast(hsum[t * H_ + k]) * cw[k];
#pragma unroll
    for (int o = 32; o; o >>= 1) p += __shfl_down(p, o);
    if (lane == 0) alpha[t] = p;
  }
  __syncthreads();

  // softmax over T_ (one wave)
  if (tid < 64) {
    float a = (tid < T_) ? alpha[tid] : -1e30f;
    float mx = a;
#pragma unroll
    for (int o = 32; o; o >>= 1) mx = fmaxf(mx, __shfl_xor(mx, o));
    float e = (tid < T_) ? __expf(a - mx) : 0.f;
    float s = e;
#pragma unroll
    for (int o = 32; o; o >>= 1) s += __shfl_xor(s, o);
    if (tid < T_) alpha[tid] = e / s;
  }
  __syncthreads();

  // r = hsum @ alpha ; hStar = tanh(r)
  for (int k = tid; k < H_; k += 256) {
    float r = 0.f;
#pragma unroll
    for (int t = 0; t < T_; t++) r += hsum[t * H_ + k] * alpha[t];
    hstar[k] = tanh_fast(r);
  }
  __syncthreads();

  // logits, wave-parallel over classes
  for (int cls = wave; cls < NC_; cls += 4) {
    float p = (lane == 0) ? fc_b[cls] : 0.f;
    for (int k = lane; k < H_; k += 64) p += hstar[k] * fc_w[(size_t)cls * H_ + k];
#pragma unroll
    for (int o = 32; o; o >>= 1) p += __shfl_down(p, o);
    if (lane == 0) lg[cls] = p;
  }
  __syncthreads();
  if (tid == 0) {
    float mx = -1e30f;
    for (int i2 = 0; i2 < NC_; i2++) mx = fmaxf(mx, lg[i2]);
    float s = 0.f;
    for (int i2 = 0; i2 < NC_; i2++) s += __expf(lg[i2] - mx);
    mxs = mx; sms = s;
  }
  __syncthreads();
  if (tid < NC_) out[(size_t)b * NC_ + tid] = __expf(lg[tid] - mxs) / sms;
}

// ---------------------------------------------------------------------------
extern "C" void kernel_launch(void* const* d_in, const int* in_sizes, int n_in,
                              void* d_out, int out_size, void* d_ws, size_t ws_size,
                              hipStream_t stream) {
  const float* x      = (const float*)d_in[0];
  const float* w_ih   = (const float*)d_in[1];
  const float* w_hh   = (const float*)d_in[2];
  const float* b_ih   = (const float*)d_in[3];
  const float* b_hh   = (const float*)d_in[4];
  const float* conv_w = (const float*)d_in[5];
  const float* fc_w   = (const float*)d_in[6];
  const float* fc_b   = (const float*)d_in[7];
  float* out = (float*)d_out;

  // Workspace carve (~432 MB)
  char* p = (char*)d_ws;
  f16* Wih = (f16*)p;   p += (size_t)NDD * HP * sizeof(f16);        // 1.64 MB
  f16* Whh = (f16*)p;   p += (size_t)NDD * HP * sizeof(f16);        // 1.64 MB
  float* bias = (float*)p; p += (size_t)NDD * sizeof(float);        // 10 KB
  p = (char*)(((uintptr_t)p + 255) & ~(uintptr_t)255);
  f16* xT = (f16*)p;    p += (size_t)T_ * B_ * HP * sizeof(f16);    // 112.7 MB
  f16* h  = (f16*)p;    p += (size_t)2 * 2 * B_ * HP * sizeof(f16); // 10.5 MB
  float* c = (float*)p; p += (size_t)2 * B_ * H_ * sizeof(float);   // 9.8 MB
  f16* hs = (f16*)p;    p += (size_t)2 * B_ * SB * sizeof(f16);     // 211.6 MB
  f16* xz = (f16*)p;    p += (size_t)XZC * B_ * NDD * sizeof(f16);  // 83.9 MB

  hipMemsetAsync(h, 0, (size_t)2 * 2 * B_ * HP * sizeof(f16), stream);
  hipMemsetAsync(c, 0, (size_t)2 * B_ * H_ * sizeof(float), stream);

  prep_weights<<<(2 * NDD * HP + 255) / 256, 256, 0, stream>>>(
      w_ih, w_hh, b_ih, b_hh, Wih, Whh, bias);
  prep_xT<<<dim3(B_, 5), 256, 0, stream>>>(x, xT);

  const size_t hstride = (size_t)2 * B_ * HP;  // ping-pong stride
  int t0 = 0;
  while (t0 < T_) {
    int cn = (T_ - t0 < XZC) ? (T_ - t0) : XZC;
    xz_gemm<<<dim3(cn * 32, 20), 256, 0, stream>>>(
        xT + (size_t)t0 * B_ * HP, Wih, xz);
    for (int tt = 0; tt < cn; ++tt) {
      int t = t0 + tt;
      lstm_step<<<dim3(10, 32, 2), 256, 0, stream>>>(
          h + (size_t)(t & 1) * hstride, h + (size_t)((t + 1) & 1) * hstride,
          c, Whh, bias, xz + (size_t)tt * B_ * NDD, hs + (size_t)t * H_);
    }
    t0 += cn;
  }

  attn<<<B_, 256, 0, stream>>>(hs, conv_w, fc_w, fc_b, out);
}

// Round 3
// 2069.302 us; speedup vs baseline: 1.4020x; 1.3323x over previous
//
#include <hip/hip_runtime.h>
#include <cstdint>
#include <cstddef>

// Problem constants
#define B_  4096
#define H_  300
#define T_  43
#define NC_ 80
#define HP  320      // padded hidden/input dim (300 -> 320)
#define ND  1280     // padded 4H per direction
#define NDD 2560     // both directions
#define TR  304      // hs per-t row length in f16 (300 + 4 zero pad, 16B aligned)
#define SB2 (T_ * TR) // hs per-(d,b) stride in f16 = 13072
#define XZC 4        // xz precompute chunk (timesteps)

typedef _Float16 f16;
typedef _Float16 half8 __attribute__((ext_vector_type(8)));
typedef _Float16 half4 __attribute__((ext_vector_type(4)));
typedef float    f32x4 __attribute__((ext_vector_type(4)));

__device__ __forceinline__ void gl_lds16(const void* g, void* l) {
  __builtin_amdgcn_global_load_lds(
      (const __attribute__((address_space(1))) void*)g,
      (__attribute__((address_space(3))) void*)l, 16, 0, 0);
}
__device__ __forceinline__ float sigmoid_(float x) {
  return 1.f / (1.f + __expf(-x));
}
__device__ __forceinline__ float tanh_fast(float x) {
  x = fminf(fmaxf(x, -15.f), 15.f);
  float e = __expf(2.f * x);
  return (e - 1.f) / (e + 1.f);
}

// ---------------------------------------------------------------------------
// Weight packing. Row index = d*1280 + 4*jh + g (gate-interleaved, order
// i,f,g,o). Wih[2560][320] (k<300 real), Whh[2560][320], bias[2560].
// ---------------------------------------------------------------------------
__global__ void prep_weights(const float* __restrict__ w_ih,
                             const float* __restrict__ w_hh,
                             const float* __restrict__ b_ih,
                             const float* __restrict__ b_hh,
                             f16* __restrict__ Wih, f16* __restrict__ Whh,
                             float* __restrict__ bias) {
  int idx = blockIdx.x * 256 + threadIdx.x;
  const int total = NDD * HP;
  if (idx < 2 * total) {
    int which = idx / total;  // 0 = Wih, 1 = Whh
    int rem = idx % total;
    int row = rem / HP, k = rem % HP;
    int d = row / ND, n = row % ND;
    int jh = n >> 2, g = n & 3;
    float v = 0.f;
    if (jh < H_ && k < H_) {
      const float* W = which ? w_hh : w_ih;
      v = W[((size_t)d * 4 * H_ + g * H_ + jh) * H_ + k];
    }
    (which ? Whh : Wih)[(size_t)row * HP + k] = (f16)v;
  }
  if (idx < NDD) {
    int d = idx / ND, n = idx % ND;
    int jh = n >> 2, g = n & 3;
    float v = 0.f;
    if (jh < H_)
      v = b_ih[d * 4 * H_ + g * H_ + jh] + b_hh[d * 4 * H_ + g * H_ + jh];
    bias[idx] = v;
  }
}

// ---------------------------------------------------------------------------
// x [B,H,T] fp32 -> xT[t*B+b][k] f16, k padded to 320 with zeros.
// ---------------------------------------------------------------------------
__global__ void prep_xT(const float* __restrict__ x, f16* __restrict__ xT) {
  __shared__ float tile[64][44];
  int b = blockIdx.x, ch = blockIdx.y;
  int h0 = ch * 64;
  for (int idx = threadIdx.x; idx < 64 * T_; idx += 256) {
    int hh = idx / T_, t = idx % T_;
    float v = 0.f;
    if (h0 + hh < H_) v = x[((size_t)b * H_ + h0 + hh) * T_ + t];
    tile[hh][t] = v;
  }
  __syncthreads();
  for (int idx = threadIdx.x; idx < 64 * T_; idx += 256) {
    int t = idx / 64, hh = idx % 64;
    xT[((size_t)t * B_ + b) * HP + h0 + hh] = (f16)tile[hh][t];
  }
}

// ---------------------------------------------------------------------------
// Precompute xz in z^T orientation, half4-gate-packed:
//   xz4[((tl*2 + d)*HP + jh)*B + b] = {z_i, z_f, z_g, z_o}  (f16 each)
// A = Wih rows (n = gates), B = xT rows (m = t_local*B + b). K = 320.
// grid (cn*32 m-tiles, 20 n-tiles).
// ---------------------------------------------------------------------------
__global__ void xz_gemm(const f16* __restrict__ Xc,   // [cn*B][320]
                        const f16* __restrict__ Wih,  // [2560][320]
                        half4* __restrict__ xz4) {
  __shared__ f16 As[128 * 32];
  __shared__ f16 Bs[128 * 32];
  const int tid = threadIdx.x;
  const int wave = tid >> 6, lane = tid & 63;
  const int mt = blockIdx.x, nt = blockIdx.y;
  const int lrow4 = lane >> 2, col8 = (lane & 3) << 3;
  const int wm = wave & 1, wn = wave >> 1;
  const int lr = lane & 15, lq = lane >> 4;
  const int kq = lq << 3;

  const f16* Ab = Wih + (size_t)nt * 128 * HP;
  const f16* Bb = Xc + (size_t)mt * 128 * HP;

  f32x4 acc[4][4];
#pragma unroll
  for (int i = 0; i < 4; i++)
#pragma unroll
    for (int j = 0; j < 4; j++) acc[i][j] = (f32x4){0.f, 0.f, 0.f, 0.f};

  for (int kt = 0; kt < HP / 32; ++kt) {
    __syncthreads();
#pragma unroll
    for (int i = 0; i < 2; i++) {
      int r0 = wave * 32 + i * 16;
      gl_lds16(Ab + (size_t)(r0 + lrow4) * HP + kt * 32 + col8, &As[r0 * 32]);
      gl_lds16(Bb + (size_t)(r0 + lrow4) * HP + kt * 32 + col8, &Bs[r0 * 32]);
    }
    __syncthreads();
    half8 af[4], bf[4];
#pragma unroll
    for (int i = 0; i < 4; i++) {
      af[i] = *(const half8*)&As[(wm * 64 + i * 16 + lr) * 32 + kq];
      bf[i] = *(const half8*)&Bs[(wn * 64 + i * 16 + lr) * 32 + kq];
    }
#pragma unroll
    for (int i = 0; i < 4; i++)
#pragma unroll
      for (int j = 0; j < 4; j++)
        acc[i][j] = __builtin_amdgcn_mfma_f32_16x16x32_f16(af[i], bf[j],
                                                           acc[i][j], 0, 0, 0);
  }

  const int dt = nt / 10;
  const int tl = mt >> 5;
#pragma unroll
  for (int i = 0; i < 4; i++) {
    const int jh = (nt % 10) * 32 + wm * 16 + i * 4 + lq;
    if (jh >= H_) continue;
#pragma unroll
    for (int j = 0; j < 4; j++) {
      const int b = (mt & 31) * 128 + wn * 64 + j * 16 + lr;
      half4 o;
#pragma unroll
      for (int r = 0; r < 4; r++) o[r] = (f16)acc[i][j][r];
      xz4[((size_t)(tl * 2 + dt) * HP + jh) * B_ + b] = o;
    }
  }
}

// ---------------------------------------------------------------------------
// One LSTM step, z^T orientation. A = Whh rows (n), B = h_prev rows (b).
// Lane's 4 acc regs = 4 gates of one jh. Epilogue: coalesced half4 xz load,
// coalesced c r/w ([d][jh][b] layout), then LDS transpose -> coalesced
// 16B-chunk h_next / hs row writes.
// grid (10 jh-tiles, 32 b-tiles, 2 dirs), 256 thr.
// ---------------------------------------------------------------------------
__global__ void lstm_step(const f16* __restrict__ h_prev,  // [2][B][320]
                          f16* __restrict__ h_next,        // [2][B][320]
                          float* __restrict__ c,           // [2][300][B]
                          const f16* __restrict__ Whh,     // [2560][320]
                          const float* __restrict__ bias,  // [2560]
                          const half4* __restrict__ xz4,   // [2][320][B] packed
                          f16* __restrict__ hs,            // [2][B][43][304]
                          int t)
{
  __shared__ __attribute__((aligned(16))) char smem[16384];
  f16* As = (f16*)smem;
  f16* Bs = (f16*)(smem + 8192);
  f16* tile = (f16*)smem;  // 32 x 136 f16 = 8704 B, reused after GEMM

  const int tid = threadIdx.x;
  const int wave = tid >> 6, lane = tid & 63;
  const int wt = blockIdx.x, bt = blockIdx.y, d = blockIdx.z;
  const int lrow4 = lane >> 2, col8 = (lane & 3) << 3;
  const int wm = wave & 1, wn = wave >> 1;
  const int lr = lane & 15, lq = lane >> 4;
  const int kq = lq << 3;

  const f16* Wb = Whh + ((size_t)d * ND + wt * 128) * HP;
  const f16* hb = h_prev + ((size_t)d * B_ + bt * 128) * HP;

  f32x4 acc[4][4];
#pragma unroll
  for (int i = 0; i < 4; i++)
#pragma unroll
    for (int j = 0; j < 4; j++) acc[i][j] = (f32x4){0.f, 0.f, 0.f, 0.f};

  for (int kt = 0; kt < HP / 32; ++kt) {
    __syncthreads();
#pragma unroll
    for (int i = 0; i < 2; i++) {
      int r0 = wave * 32 + i * 16;
      gl_lds16(Wb + (size_t)(r0 + lrow4) * HP + kt * 32 + col8, &As[r0 * 32]);
      gl_lds16(hb + (size_t)(r0 + lrow4) * HP + kt * 32 + col8, &Bs[r0 * 32]);
    }
    __syncthreads();
    half8 af[4], bf[4];
#pragma unroll
    for (int i = 0; i < 4; i++) {
      af[i] = *(const half8*)&As[(wm * 64 + i * 16 + lr) * 32 + kq];
      bf[i] = *(const half8*)&Bs[(wn * 64 + i * 16 + lr) * 32 + kq];
    }
#pragma unroll
    for (int i = 0; i < 4; i++)
#pragma unroll
      for (int j = 0; j < 4; j++)
        acc[i][j] = __builtin_amdgcn_mfma_f32_16x16x32_f16(af[i], bf[j],
                                                           acc[i][j], 0, 0, 0);
  }

  __syncthreads();  // all LDS reads done before tile reuse

  // Gate epilogue -> stage hn into LDS tile [jh_local][b_local], stride 136.
#pragma unroll
  for (int i = 0; i < 4; i++) {
    const int jl = wm * 16 + i * 4 + lq;  // 0..31
    const int jh = wt * 32 + jl;
    float4 b4 = {0.f, 0.f, 0.f, 0.f};
    if (jh < H_) b4 = *(const float4*)&bias[d * ND + 4 * jh];
#pragma unroll
    for (int j = 0; j < 4; j++) {
      const int bl = wn * 64 + j * 16 + lr;  // 0..127
      const int b = bt * 128 + bl;
      f16 hnv = (f16)0.f;
      if (jh < H_) {
        const half4 x4 = xz4[((size_t)d * HP + jh) * B_ + b];
        float zi = acc[i][j][0] + b4.x + (float)x4[0];
        float zf = acc[i][j][1] + b4.y + (float)x4[1];
        float zg = acc[i][j][2] + b4.z + (float)x4[2];
        float zo = acc[i][j][3] + b4.w + (float)x4[3];
        const size_t cidx = ((size_t)d * H_ + jh) * B_ + b;
        float co = c[cidx];
        float cn = sigmoid_(zf) * co + sigmoid_(zi) * tanh_fast(zg);
        float hn = sigmoid_(zo) * tanh_fast(cn);
        c[cidx] = cn;
        hnv = (f16)hn;
      }
      tile[jl * 136 + bl] = hnv;
    }
  }
  __syncthreads();

  // Coalesced write-out: thread -> (b_local = tid>>1, 16-jh half = tid&1).
  {
    const int bl = tid >> 1, jhalf = tid & 1;
    const int b = bt * 128 + bl;
    f16 vals[16];
#pragma unroll
    for (int jj = 0; jj < 16; jj++)
      vals[jj] = tile[(jhalf * 16 + jj) * 136 + bl];
    half8 v0, v1;
#pragma unroll
    for (int r = 0; r < 8; r++) { v0[r] = vals[r]; v1[r] = vals[8 + r]; }

    const int jh0 = wt * 32 + jhalf * 16;
    f16* hdst = h_next + ((size_t)d * B_ + b) * HP + jh0;
    *(half8*)hdst = v0;
    *(half8*)(hdst + 8) = v1;

    if (jh0 < H_) {  // wt==9,jhalf==1 (jh 304..319) has no hs slot
      f16* sdst = hs + ((size_t)d * B_ + b) * SB2 + t * TR + jh0;
      *(half8*)sdst = v0;      // wt==9: jh 288..295 valid
      *(half8*)(sdst + 8) = v1;  // wt==9: 296..299 valid + 4 zeros -> row pad
    }
  }
}

// ---------------------------------------------------------------------------
// attn1: alpha[b][t] = softmax_t( sum_h tanh(hs0+hs1) * conv_w[h] ).
// Pure stream over hs; half4 loads (rows are 304-wide, zero-padded).
// ---------------------------------------------------------------------------
__global__ __launch_bounds__(256) void attn1(const f16* __restrict__ hs,
                                             const float* __restrict__ conv_w,
                                             float* __restrict__ alpha_g) {
  __shared__ float cw[TR];
  __shared__ float red[48];
  const int b = blockIdx.x, tid = threadIdx.x;
  const int wave = tid >> 6, lane = tid & 63;
  for (int k = tid; k < TR; k += 256) cw[k] = (k < H_) ? conv_w[k] : 0.f;
  __syncthreads();

  const half4* s0 = (const half4*)(hs + (size_t)b * SB2);
  const half4* s1 = (const half4*)(hs + (size_t)(B_ + b) * SB2);
  for (int t = wave; t < T_; t += 4) {
    const int base = t * (TR / 4);
    float p = 0.f;
    {
      half4 a = s0[base + lane], cc = s1[base + lane];
#pragma unroll
      for (int r = 0; r < 4; r++)
        p += tanh_fast((float)a[r] + (float)cc[r]) * cw[lane * 4 + r];
    }
    if (lane < 12) {
      half4 a = s0[base + 64 + lane], cc = s1[base + 64 + lane];
#pragma unroll
      for (int r = 0; r < 4; r++)
        p += tanh_fast((float)a[r] + (float)cc[r]) * cw[256 + lane * 4 + r];
    }
#pragma unroll
    for (int o = 32; o; o >>= 1) p += __shfl_down(p, o);
    if (lane == 0) red[t] = p;
  }
  __syncthreads();
  if (tid < 64) {
    float a = (tid < T_) ? red[tid] : -1e30f;
    float mx = a;
#pragma unroll
    for (int o = 32; o; o >>= 1) mx = fmaxf(mx, __shfl_xor(mx, o));
    float e = (tid < T_) ? __expf(a - mx) : 0.f;
    float s = e;
#pragma unroll
    for (int o = 32; o; o >>= 1) s += __shfl_xor(s, o);
    if (tid < T_) alpha_g[(size_t)b * 44 + tid] = e / s;
  }
}

// ---------------------------------------------------------------------------
// attn2: r[b][h] = sum_t hsum*alpha; hstar = tanh(r); logits; softmax.
// Thread-per-h accumulation, coalesced streaming.
// ---------------------------------------------------------------------------
__global__ __launch_bounds__(256) void attn2(const f16* __restrict__ hs,
                                             const float* __restrict__ alpha_g,
                                             const float* __restrict__ fc_w,
                                             const float* __restrict__ fc_b,
                                             float* __restrict__ out) {
  __shared__ float al[T_];
  __shared__ float hstar[TR];
  __shared__ float lg[NC_];
  const int b = blockIdx.x, tid = threadIdx.x;
  if (tid < T_) al[tid] = alpha_g[(size_t)b * 44 + tid];
  __syncthreads();

  const f16* s0 = hs + (size_t)b * SB2;
  const f16* s1 = hs + (size_t)(B_ + b) * SB2;
  float r0 = 0.f, r1 = 0.f;
  for (int t = 0; t < T_; t++) {
    const float a = al[t];
    r0 += ((float)s0[t * TR + tid] + (float)s1[t * TR + tid]) * a;
    if (tid < 48)
      r1 += ((float)s0[t * TR + 256 + tid] + (float)s1[t * TR + 256 + tid]) * a;
  }
  hstar[tid] = tanh_fast(r0);
  if (tid < 48) hstar[256 + tid] = tanh_fast(r1);
  __syncthreads();

  const int wave = tid >> 6, lane = tid & 63;
  for (int cls = wave; cls < NC_; cls += 4) {
    float p = 0.f;
    for (int k = lane; k < H_; k += 64) p += hstar[k] * fc_w[(size_t)cls * H_ + k];
#pragma unroll
    for (int o = 32; o; o >>= 1) p += __shfl_down(p, o);
    if (lane == 0) lg[cls] = p + fc_b[cls];
  }
  __syncthreads();
  if (tid < 64) {
    float a0 = (tid < 40) ? lg[tid] : -1e30f;
    float a1 = (tid < 40) ? lg[tid + 40] : -1e30f;
    float mx = fmaxf(a0, a1);
#pragma unroll
    for (int o = 32; o; o >>= 1) mx = fmaxf(mx, __shfl_xor(mx, o));
    float e0 = (tid < 40) ? __expf(a0 - mx) : 0.f;
    float e1 = (tid < 40) ? __expf(a1 - mx) : 0.f;
    float s = e0 + e1;
#pragma unroll
    for (int o = 32; o; o >>= 1) s += __shfl_xor(s, o);
    if (tid < 40) {
      out[(size_t)b * NC_ + tid] = e0 / s;
      out[(size_t)b * NC_ + tid + 40] = e1 / s;
    }
  }
}

// ---------------------------------------------------------------------------
extern "C" void kernel_launch(void* const* d_in, const int* in_sizes, int n_in,
                              void* d_out, int out_size, void* d_ws, size_t ws_size,
                              hipStream_t stream) {
  const float* x      = (const float*)d_in[0];
  const float* w_ih   = (const float*)d_in[1];
  const float* w_hh   = (const float*)d_in[2];
  const float* b_ih   = (const float*)d_in[3];
  const float* b_hh   = (const float*)d_in[4];
  const float* conv_w = (const float*)d_in[5];
  const float* fc_w   = (const float*)d_in[6];
  const float* fc_b   = (const float*)d_in[7];
  float* out = (float*)d_out;

  // Workspace carve (~436 MB)
  char* p = (char*)d_ws;
  f16* Wih = (f16*)p;   p += (size_t)NDD * HP * sizeof(f16);
  f16* Whh = (f16*)p;   p += (size_t)NDD * HP * sizeof(f16);
  float* bias = (float*)p; p += (size_t)NDD * sizeof(float);
  p = (char*)(((uintptr_t)p + 255) & ~(uintptr_t)255);
  f16* xT = (f16*)p;    p += (size_t)T_ * B_ * HP * sizeof(f16);    // 112.7 MB
  f16* h  = (f16*)p;    p += (size_t)2 * 2 * B_ * HP * sizeof(f16); // 10.5 MB
  float* c = (float*)p; p += (size_t)2 * B_ * H_ * sizeof(float);   // 9.8 MB
  f16* hs = (f16*)p;    p += (size_t)2 * B_ * SB2 * sizeof(f16);    // 214.2 MB
  half4* xz = (half4*)p; p += (size_t)XZC * 2 * HP * B_ * sizeof(half4); // 83.9 MB
  float* alpha_g = (float*)p; p += (size_t)B_ * 44 * sizeof(float); // 0.72 MB

  hipMemsetAsync(h, 0, (size_t)2 * 2 * B_ * HP * sizeof(f16), stream);
  hipMemsetAsync(c, 0, (size_t)2 * B_ * H_ * sizeof(float), stream);

  prep_weights<<<(2 * NDD * HP + 255) / 256, 256, 0, stream>>>(
      w_ih, w_hh, b_ih, b_hh, Wih, Whh, bias);
  prep_xT<<<dim3(B_, 5), 256, 0, stream>>>(x, xT);

  const size_t hstride = (size_t)2 * B_ * HP;  // ping-pong stride
  const size_t xzslab = (size_t)2 * HP * B_;   // half4 units per t_local
  int t0 = 0;
  while (t0 < T_) {
    int cn = (T_ - t0 < XZC) ? (T_ - t0) : XZC;
    xz_gemm<<<dim3(cn * 32, 20), 256, 0, stream>>>(
        xT + (size_t)t0 * B_ * HP, Wih, xz);
    for (int tt = 0; tt < cn; ++tt) {
      int t = t0 + tt;
      lstm_step<<<dim3(10, 32, 2), 256, 0, stream>>>(
          h + (size_t)(t & 1) * hstride, h + (size_t)((t + 1) & 1) * hstride,
          c, Whh, bias, xz + (size_t)tt * xzslab, hs, t);
    }
    t0 += cn;
  }

  attn1<<<B_, 256, 0, stream>>>(hs, conv_w, alpha_g);
  attn2<<<B_, 256, 0, stream>>>(hs, alpha_g, fc_w, fc_b, out);
}